// Round 5
// baseline (1717.687 us; speedup 1.0000x reference)
//
#include <hip/hip_runtime.h>

typedef __attribute__((ext_vector_type(8))) short bf16x8;
typedef __attribute__((ext_vector_type(4))) float f32x4;

#define T_STEPS 96
#define BATCH 64
#define HID 2048
#define NGATE 8192

#define AS1 __attribute__((address_space(1)))
#define AS3 __attribute__((address_space(3)))

__device__ inline unsigned short f2bf(float f) {
  union { float f; unsigned u; } x; x.f = f;
  unsigned r = x.u + 0x7fffu + ((x.u >> 16) & 1u);
  return (unsigned short)(r >> 16);
}
__device__ inline float bf2f(unsigned short b) {
  union { unsigned u; float f; } x; x.u = ((unsigned)b) << 16;
  return x.f;
}
__device__ inline float sigm(float x) { return 1.f / (1.f + __expf(-x)); }
__device__ inline float tanh_(float x) { return 1.f - 2.f / (__expf(2.f * x) + 1.f); }

// ---------------------------------------------------------------- cast f32->bf16
__global__ __launch_bounds__(256) void cast_bf16(const float* __restrict__ in,
                                                 unsigned short* __restrict__ out,
                                                 int n4) {
  int i = blockIdx.x * 256 + threadIdx.x;
  if (i >= n4) return;
  float4 v = ((const float4*)in)[i];
  ushort4 o;
  o.x = f2bf(v.x); o.y = f2bf(v.y); o.z = f2bf(v.z); o.w = f2bf(v.w);
  ((ushort4*)out)[i] = o;
}

// ---------------------------------------------------------------- gumbel (threefry, partitionable)
__global__ void gumbel_k(float* __restrict__ g) {
  int p = blockIdx.x * blockDim.x + threadIdx.x;
  if (p >= 12288) return;
  const unsigned k1 = 0u, k2 = 42u;
  unsigned ks[3] = { k1, k2, 0x1BD11BDAu ^ k1 ^ k2 };
  unsigned x0 = 0u + ks[0];
  unsigned x1 = (unsigned)p + ks[1];
  const int rot[2][4] = { {13, 15, 26, 6}, {17, 29, 16, 24} };
  #pragma unroll
  for (int i = 0; i < 5; ++i) {
    #pragma unroll
    for (int j = 0; j < 4; ++j) {
      int r = rot[i & 1][j];
      x0 += x1;
      x1 = (x1 << r) | (x1 >> (32 - r));
      x1 ^= x0;
    }
    x0 += ks[(i + 1) % 3];
    x1 += ks[(i + 2) % 3] + (unsigned)(i + 1);
  }
  unsigned bits = x0 ^ x1;
  union { unsigned u; float f; } v; v.u = (bits >> 9) | 0x3f800000u;
  float f = v.f - 1.f;
  const float tiny = 1.17549435e-38f;
  float u = fmaxf(tiny, f * (1.f - tiny) + tiny);
  g[p] = -logf(-logf(u));
}

// ---------------------------------------------------------------- phase-1 GEMM (unchanged)
__global__ __launch_bounds__(256) void gemm_xg(
    const unsigned short* __restrict__ A,
    const unsigned short* __restrict__ W,
    const float* __restrict__ b_ih, const float* __restrict__ b_hh,
    unsigned short* __restrict__ xg) {
  __shared__ unsigned short As[128 * 32];
  __shared__ unsigned short Bs[128 * 32];
  int bid = blockIdx.x;
  int nb = bid & 63, mb = bid >> 6;
  int m0 = mb * 128, n0 = nb * 128;
  int tid = threadIdx.x, w = tid >> 6, l = tid & 63;
  int lr = l & 15, lg = l >> 4;
  int wm = (w & 1) * 64, wn = (w >> 1) * 64;
  f32x4 acc[4][4] = {};
  int e0 = w * 512 + l * 8;
  for (int k0 = 0; k0 < 2048; k0 += 32) {
    __syncthreads();
    #pragma unroll
    for (int j = 0; j < 2; ++j) {
      int e = j * 2048 + e0;
      int r = e >> 5, c = e & 31;
      const unsigned short* ga = A + (long)(m0 + r) * 2048 + k0 + c;
      const unsigned short* gb = W + (long)(n0 + r) * 2048 + k0 + c;
      __builtin_amdgcn_global_load_lds(
          (const AS1 unsigned int*)ga,
          (AS3 unsigned int*)&As[j * 2048 + w * 512], 16, 0, 0);
      __builtin_amdgcn_global_load_lds(
          (const AS1 unsigned int*)gb,
          (AS3 unsigned int*)&Bs[j * 2048 + w * 512], 16, 0, 0);
    }
    __syncthreads();
    bf16x8 av[4], bv[4];
    #pragma unroll
    for (int i = 0; i < 4; ++i)
      av[i] = *(const bf16x8*)&As[(wm + i * 16 + lr) * 32 + lg * 8];
    #pragma unroll
    for (int i = 0; i < 4; ++i)
      bv[i] = *(const bf16x8*)&Bs[(wn + i * 16 + lr) * 32 + lg * 8];
    #pragma unroll
    for (int i = 0; i < 4; ++i)
      #pragma unroll
      for (int j = 0; j < 4; ++j)
        acc[i][j] = __builtin_amdgcn_mfma_f32_16x16x32_bf16(av[i], bv[j], acc[i][j], 0, 0, 0);
  }
  #pragma unroll
  for (int j = 0; j < 4; ++j) {
    int n = n0 + wn + j * 16 + lr;
    float bias = b_ih[n] + b_hh[n];
    #pragma unroll
    for (int i = 0; i < 4; ++i) {
      #pragma unroll
      for (int r = 0; r < 4; ++r) {
        int m = m0 + wm + i * 16 + lg * 4 + r;
        int bb = m / 96;
        int tt = m - bb * 96;
        long row = (long)tt * 64 + bb;
        xg[row * 8192 + n] = f2bf(acc[i][j][r] + bias);
      }
    }
  }
}

// ---------------------------------------------------------------- recurrent step
// grid 256 (block cb: 8 h-cols x 4 gates = 32 gate-rows), block 512 = 8 waves.
// Wave w owns K-slice [w*256, w*256+256). Each wave computes the FULL 64x32
// block tile over its K-slice: 4 a-frags x 2 b-frags -> 8 MFMA per K=32, all
// operands loaded per-lane DIRECT from global (L2-resident H and W, each byte
// touched once per block). No LDS, no barriers in the K-loop. Partials are
// combined via a 64 KB LDS buffer (batch-XOR swizzle) + one syncthreads, then
// the fused gate/c/h epilogue. xg/Cstate prefetched before the K-loop.
__global__ __launch_bounds__(512) void lstm_step(
    const unsigned short* __restrict__ Whh,   // (8192,2048) bf16
    const unsigned short* __restrict__ xg,    // (96,64,8192) bf16
    const unsigned short* __restrict__ Hprev, // (64,2048) bf16
    unsigned short* __restrict__ Hnext,       // (64,2048) bf16
    unsigned short* __restrict__ Call_t,      // (64,2048) bf16 snapshot
    float* __restrict__ Cstate,               // (64,2048) f32
    int t) {
  __shared__ float gl[8 * 2048];              // [w:8][nn:32][batch:64 ^ swz]
  const int cb = blockIdx.x;
  const int tid = threadIdx.x;
  const int w = tid >> 6, l = tid & 63;
  const int lr = l & 15, lg = l >> 4;

  // ---- epilogue prefetch (T14): xg gates + Cstate for this thread's cell
  const int eb = tid >> 3;                    // batch 0..63
  const int ej = tid & 7;                     // col 0..7
  const unsigned short* xrow = xg + ((long)t * 64 + eb) * 8192 + cb * 8 + ej;
  const unsigned short x_i = xrow[0];
  const unsigned short x_f = xrow[2048];
  const unsigned short x_g = xrow[4096];
  const unsigned short x_o = xrow[6144];
  const long ci = (long)eb * 2048 + cb * 8 + ej;
  const float cprev = Cstate[ci];

  // ---- K-loop: pure register GEMM, direct global operands
  f32x4 acc[4][2] = {};
  const int kbase = w * 256 + lg * 8;
  const unsigned short* Arow = Hprev + (long)lr * 2048 + kbase;
  // B rows: nn = nf*16 + lr -> global gate-row (nn>>3)*2048 + cb*8 + (nn&7)
  const unsigned short* Brow0 =
      Whh + ((long)((lr >> 3) * 2048 + cb * 8 + (lr & 7))) * 2048 + kbase;
  const unsigned short* Brow1 =
      Whh + ((long)(((16 + lr) >> 3) * 2048 + cb * 8 + (lr & 7))) * 2048 + kbase;
  #pragma unroll
  for (int ks = 0; ks < 8; ++ks) {
    const int ko = ks * 32;
    bf16x8 b0 = *(const bf16x8*)(Brow0 + ko);
    bf16x8 b1 = *(const bf16x8*)(Brow1 + ko);
    #pragma unroll
    for (int mf = 0; mf < 4; ++mf) {
      bf16x8 a = *(const bf16x8*)(Arow + (long)mf * 16 * 2048 + ko);
      acc[mf][0] = __builtin_amdgcn_mfma_f32_16x16x32_bf16(a, b0, acc[mf][0], 0, 0, 0);
      acc[mf][1] = __builtin_amdgcn_mfma_f32_16x16x32_bf16(a, b1, acc[mf][1], 0, 0, 0);
    }
  }

  // ---- write partials to gl (batch index XOR-swizzled by (nn&7)<<3)
  #pragma unroll
  for (int nf = 0; nf < 2; ++nf) {
    const int nn = nf * 16 + lr;
    const int bx = (nn & 7) << 3;
    #pragma unroll
    for (int mf = 0; mf < 4; ++mf) {
      const int b0i = (mf * 16 + lg * 4) ^ bx;   // +r stays consecutive (r<4)
      *(f32x4*)&gl[w * 2048 + nn * 64 + b0i] = acc[mf][nf];
    }
  }
  __syncthreads();

  // ---- combine 8 K-partials + fused LSTM cell update
  float sum[4];
  #pragma unroll
  for (int g = 0; g < 4; ++g) {
    const int nn = g * 8 + ej;
    const int base = nn * 64 + (eb ^ ((nn & 7) << 3));
    float s = 0.f;
    #pragma unroll
    for (int ww = 0; ww < 8; ++ww) s += gl[ww * 2048 + base];
    sum[g] = s;
  }
  const float iv = sum[0] + bf2f(x_i);
  const float fv = sum[1] + bf2f(x_f);
  const float gv = sum[2] + bf2f(x_g);
  const float ov = sum[3] + bf2f(x_o);
  const float c = sigm(fv) * cprev + sigm(iv) * tanh_(gv);
  const float h = sigm(ov) * tanh_(c);
  Cstate[ci] = c;
  Call_t[ci] = f2bf(c);
  Hnext[ci] = f2bf(h);
}

// ---------------------------------------------------------------- heads (unchanged)
__global__ __launch_bounds__(256) void heads(
    const unsigned short* __restrict__ Hall,
    const unsigned short* __restrict__ Call,
    const float* __restrict__ Wp, const float* __restrict__ bp,
    const float* __restrict__ Wpc, const float* __restrict__ bpc,
    const float* __restrict__ Wu, const float* __restrict__ bu,
    const float* __restrict__ Wuse, const float* __restrict__ buse,
    const float* __restrict__ gum,
    float* __restrict__ out) {
  int p = blockIdx.x * 4 + (threadIdx.x >> 6);
  int l = threadIdx.x & 63;
  int t = p >> 6, b = p & 63;
  const unsigned short* h = Hall + ((long)(t + 1) * 64 + b) * 2048;
  const unsigned short* c = Call + ((long)t * 64 + b) * 2048;
  float s0 = 0, s1 = 0, sc0 = 0, sc1 = 0, su = 0, q0 = 0, q1 = 0;
  #pragma unroll
  for (int j = 0; j < 8; ++j) {
    int k = j * 256 + l * 4;
    ushort4 hv = *(const ushort4*)(h + k);
    ushort4 cv = *(const ushort4*)(c + k);
    float hf0 = bf2f(hv.x), hf1 = bf2f(hv.y), hf2 = bf2f(hv.z), hf3 = bf2f(hv.w);
    float cf0 = bf2f(cv.x), cf1 = bf2f(cv.y), cf2 = bf2f(cv.z), cf3 = bf2f(cv.w);
    float4 w0 = *(const float4*)(Wp + k);
    float4 w1 = *(const float4*)(Wp + 2048 + k);
    float4 w2 = *(const float4*)(Wpc + k);
    float4 w3 = *(const float4*)(Wpc + 2048 + k);
    float4 w4 = *(const float4*)(Wu + k);
    float4 w5 = *(const float4*)(Wuse + k);
    float4 w6 = *(const float4*)(Wuse + 2048 + k);
    s0 += hf0 * w0.x + hf1 * w0.y + hf2 * w0.z + hf3 * w0.w;
    s1 += hf0 * w1.x + hf1 * w1.y + hf2 * w1.z + hf3 * w1.w;
    sc0 += cf0 * w2.x + cf1 * w2.y + cf2 * w2.z + cf3 * w2.w;
    sc1 += cf0 * w3.x + cf1 * w3.y + cf2 * w3.z + cf3 * w3.w;
    su += hf0 * w4.x + hf1 * w4.y + hf2 * w4.z + hf3 * w4.w;
    q0 += hf0 * w5.x + hf1 * w5.y + hf2 * w5.z + hf3 * w5.w;
    q1 += hf0 * w6.x + hf1 * w6.y + hf2 * w6.z + hf3 * w6.w;
  }
  #pragma unroll
  for (int off = 32; off > 0; off >>= 1) {
    s0 += __shfl_xor(s0, off);
    s1 += __shfl_xor(s1, off);
    sc0 += __shfl_xor(sc0, off);
    sc1 += __shfl_xor(sc1, off);
    su += __shfl_xor(su, off);
    q0 += __shfl_xor(q0, off);
    q1 += __shfl_xor(q1, off);
  }
  if (l == 0) {
    out[(p << 1)] = s0 + bp[0];
    out[(p << 1) + 1] = s1 + bp[1];
    out[12288 + (p << 1)] = sc0 + bpc[0];
    out[12288 + (p << 1) + 1] = sc1 + bpc[1];
    out[24576 + p] = su + bu[0];
    float u0 = q0 + buse[0] + gum[p * 2];
    float u1 = q1 + buse[1] + gum[p * 2 + 1];
    float m = fmaxf(u0, u1);
    float x0 = expf(u0 - m), x1 = expf(u1 - m);
    float inv = 1.f / (x0 + x1);
    if (t >= 1) {
      out[30720 + ((t - 1) * 64 + b) * 2] = x0 * inv;
      out[30720 + ((t - 1) * 64 + b) * 2 + 1] = x1 * inv;
    }
  }
}

// ---------------------------------------------------------------- launch
extern "C" void kernel_launch(void* const* d_in, const int* in_sizes, int n_in,
                              void* d_out, int out_size, void* d_ws, size_t ws_size,
                              hipStream_t stream) {
  const float* feature  = (const float*)d_in[0];
  const float* W_ih     = (const float*)d_in[1];
  const float* W_hh     = (const float*)d_in[2];
  const float* b_ih     = (const float*)d_in[3];
  const float* b_hh     = (const float*)d_in[4];
  const float* W_pred   = (const float*)d_in[5];
  const float* b_pred   = (const float*)d_in[6];
  const float* W_pred_c = (const float*)d_in[7];
  const float* b_pred_c = (const float*)d_in[8];
  const float* W_util   = (const float*)d_in[9];
  const float* b_util   = (const float*)d_in[10];
  const float* W_use    = (const float*)d_in[11];
  const float* b_use    = (const float*)d_in[12];

  char* ws = (char*)d_ws;
  unsigned short* Abf  = (unsigned short*)(ws + 0);
  unsigned short* Call = (unsigned short*)(ws + 0);       // aliases Abf after phase 1
  unsigned short* Wbf  = (unsigned short*)(ws + 25165824L);
  unsigned short* xg   = (unsigned short*)(ws + 58720256L);
  unsigned short* Hall = (unsigned short*)(ws + 159383552L);
  float* Cstate        = (float*)(ws + 184811520L);
  float* gum           = (float*)(ws + 185335808L);
  float* out = (float*)d_out;

  hipMemsetAsync(Hall, 0, (size_t)BATCH * HID * 2, stream);
  hipMemsetAsync(Cstate, 0, (size_t)BATCH * HID * 4, stream);

  gumbel_k<<<48, 256, 0, stream>>>(gum);

  cast_bf16<<<(12582912 / 4) / 256, 256, 0, stream>>>(feature, Abf, 12582912 / 4);
  cast_bf16<<<(16777216 / 4) / 256, 256, 0, stream>>>(W_ih, Wbf, 16777216 / 4);

  gemm_xg<<<3072, 256, 0, stream>>>(Abf, Wbf, b_ih, b_hh, xg);

  cast_bf16<<<(16777216 / 4) / 256, 256, 0, stream>>>(W_hh, Wbf, 16777216 / 4);

  for (int t = 0; t < T_STEPS; ++t) {
    lstm_step<<<256, 512, 0, stream>>>(
        Wbf, xg,
        Hall + (long)t * BATCH * HID,
        Hall + (long)(t + 1) * BATCH * HID,
        Call + (long)t * BATCH * HID,
        Cstate, t);
  }

  heads<<<1536, 256, 0, stream>>>(Hall, Call,
                                  W_pred, b_pred, W_pred_c, b_pred_c,
                                  W_util, b_util, W_use, b_use,
                                  gum, out);
}